// Round 6
// baseline (337.993 us; speedup 1.0000x reference)
//
#include <hip/hip_runtime.h>
#include <math.h>
#include <stdint.h>

#define H 512
#define W 512
#define NPIX (H * W)          // 262144
#define NB 2
#define NF 180
#define KS 17
#define WSCALE 1024.0f        // exact power of two; cancels in both outputs

// LDS pool layout (u32 offsets)
#define RAW_OFF 0             // raw rows: 18*80 = 1440
#define PH_OFF  1440          // planeH (ah entries): 18*72*4 = 5184
#define PL_OFF  6624          // planeL (al entries): 5184
#define BB_OFF  11808         // B chunks, double-buffered: 2*3072 = 6144
#define POOL_U32 17952        // 71808 bytes -> 2 blocks/CU

typedef _Float16 half8 __attribute__((ext_vector_type(8)));
typedef float floatx16 __attribute__((ext_vector_type(16)));
typedef uint32_t u32x4 __attribute__((ext_vector_type(4)));

union FragU { u32x4 u; half8 h; };

__device__ inline void gl_lds16(const uint32_t* g, uint32_t* l) {
  __builtin_amdgcn_global_load_lds((const __attribute__((address_space(1))) void*)g,
                                   (__attribute__((address_space(3))) void*)l, 16, 0, 0);
}

// ---------------- taps (match numpy float64 _gauss1d) ----------------
__global__ void k_taps(float* __restrict__ taps) {
  if (threadIdx.x == 0 && blockIdx.x == 0) {
    {
      double k[5], s = 0.0;
      for (int i = 0; i < 5; i++) { double xv = (double)(i - 2) / 0.4; k[i] = exp(-0.5 * xv * xv); s += k[i]; }
      for (int i = 0; i < 5; i++) taps[i] = (float)(k[i] / s);
    }
    {
      double k[81], s = 0.0;
      for (int i = 0; i < 81; i++) { double xv = (double)(i - 40) / 10.0; k[i] = exp(-0.5 * xv * xv); s += k[i]; }
      for (int i = 0; i < 81; i++) taps[8 + i] = (float)(k[i] / s);
    }
  }
}

// ---------------- weight repack into MFMA B-fragment order, f16 split ----------------
// Bf layout (u32): chunk c (19): [c*3072 ..]: hi frags: t*256 + lane*4 + q ; lo at +1536
// B[k][n]: n = t*32 + (lane&31), k = 8*(lane>>5) + j, dword q holds j=2q (lo16), j=2q+1 (hi16)
// chunks: c<17: (ky=c, kx=k); c==17: (ky=k, kx=16); c==18: k==0 -> (ky=16,kx=16)
__global__ void k_repackB(const float* __restrict__ w, uint32_t* __restrict__ Bf) {
  int tid = blockIdx.x * 256 + threadIdx.x;
  if (tid >= 19 * 6 * 64 * 4) return;
  int q = tid & 3;
  int lane = (tid >> 2) & 63;
  int ct = tid >> 8;
  int t = ct % 6, c = ct / 6;
  int n = t * 32 + (lane & 31);
  int hf = lane >> 5;
  uint32_t hv = 0, lv = 0;
  for (int s = 0; s < 2; s++) {
    int j = 2 * q + s;
    int k = hf * 8 + j;   // 0..15
    float val = 0.f;
    if (n < NF) {
      if (c < 17)       val = w[n * 289 + c * 17 + k];
      else if (c == 17) val = w[n * 289 + k * 17 + 16];
      else if (k == 0)  val = w[n * 289 + 16 * 17 + 16];
    }
    val *= WSCALE;
    _Float16 hh = (_Float16)val;
    _Float16 ll = (_Float16)(val - (float)hh);
    hv |= (uint32_t)__builtin_bit_cast(uint16_t, hh) << (16 * s);
    lv |= (uint32_t)__builtin_bit_cast(uint16_t, ll) << (16 * s);
  }
  int base = c * 3072;
  int off = t * 256 + lane * 4 + q;
  Bf[base + off] = hv;
  Bf[base + 1536 + off] = lv;
}

// ---------------- gray ----------------
__global__ void k_gray(const float* __restrict__ x, float* __restrict__ gray) {
  int i = blockIdx.x * blockDim.x + threadIdx.x;
  if (i >= NB * NPIX) return;
  int b = i / NPIX, r = i % NPIX;
  const float* xb = x + (size_t)b * 3 * NPIX;
  gray[i] = 0.2989f * xb[r] + 0.587f * xb[NPIX + r] + 0.114f * xb[2 * NPIX + r];
}

// ---------------- vertical blur, both sigmas fused ----------------
__global__ void k_vblur2(const float* __restrict__ in, float* __restrict__ outA,
                         float* __restrict__ outB, const float* __restrict__ taps) {
  int i = blockIdx.x * blockDim.x + threadIdx.x;
  if (i >= NB * NPIX) return;
  int b = i / NPIX, r = i % NPIX;
  int y = r / W, xx = r % W;
  const float* img = in + (size_t)b * NPIX;
  float a = 0.f;
#pragma unroll
  for (int j = -2; j <= 2; j++) {
    int yy = y + j; yy = yy < 0 ? 0 : (yy > H - 1 ? H - 1 : yy);
    a = fmaf(taps[j + 2], img[yy * W + xx], a);
  }
  float c = 0.f;
  for (int j = -40; j <= 40; j++) {
    int yy = y + j; yy = yy < 0 ? 0 : (yy > H - 1 ? H - 1 : yy);
    c = fmaf(taps[8 + j + 40], img[yy * W + xx], c);
  }
  outA[i] = a;
  outB[i] = c;
}

// ---------------- horizontal blur + DoG + f16-split pack ----------------
__global__ void k_hblur_dog(const float* __restrict__ inA, const float* __restrict__ inB,
                            uint32_t* __restrict__ dogp, const float* __restrict__ taps) {
  int i = blockIdx.x * blockDim.x + threadIdx.x;
  if (i >= NB * NPIX) return;
  int b = i / NPIX, r = i % NPIX;
  int y = r / W, xx = r % W;
  const float* ra = inA + (size_t)b * NPIX + (size_t)y * W;
  const float* rb = inB + (size_t)b * NPIX + (size_t)y * W;
  float a = 0.f;
#pragma unroll
  for (int j = -2; j <= 2; j++) {
    int xc = xx + j; xc = xc < 0 ? 0 : (xc > W - 1 ? W - 1 : xc);
    a = fmaf(taps[j + 2], ra[xc], a);
  }
  float c = 0.f;
  for (int j = -40; j <= 40; j++) {
    int xc = xx + j; xc = xc < 0 ? 0 : (xc > W - 1 ? W - 1 : xc);
    c = fmaf(taps[8 + j + 40], rb[xc], c);
  }
  float d = a - c;
  _Float16 hh = (_Float16)d;
  _Float16 ll = (_Float16)(d - (float)hh);
  dogp[i] = ((uint32_t)__builtin_bit_cast(uint16_t, ll) << 16) |
            (uint32_t)__builtin_bit_cast(uint16_t, hh);
}

// ---------------- main: implicit-GEMM MFMA conv ----------------
// block: 256 thr = 4 waves; wave w = r*2+g: r = row (0..1), g = n-group (0..1)
// wave tile: M=64 px (2 m-tiles), N=96 (3 n-tiles), acc=96 VGPR.
// A frags: LDS im2col planes -> one contiguous ds_read_b128 per frag-half (no perms).
// B: global_load_lds staged per chunk, double-buffered, shared by block.
__launch_bounds__(256, 2)
__global__ void k_conv(const uint32_t* __restrict__ dogp,
                       const uint32_t* __restrict__ Bf,
                       const float* __restrict__ bins,
                       float* __restrict__ out) {
  __shared__ uint32_t pool[POOL_U32];

  const int b  = blockIdx.z;
  const int y0 = blockIdx.y * 2;
  const int x0 = blockIdx.x * 64;
  const int tid = threadIdx.x;
  const int lane = tid & 63;
  const int w  = __builtin_amdgcn_readfirstlane(tid >> 6);  // 0..3
  const int r  = w >> 1;        // row within block
  const int g  = w & 1;         // n-group (filters g*96 .. g*96+95)
  const int nl = lane & 31;
  const int half = lane >> 5;

  // ---- stage raw rows y0-8 .. y0+9, x0-8 .. x0+71 (zero-padded) ----
  const uint32_t* dgb = dogp + (size_t)b * NPIX;
  for (int i = tid; i < 18 * 80; i += 256) {
    int ry = i / 80, rx = i % 80;
    int gy = y0 + ry - 8, gx = x0 + rx - 8;
    uint32_t v = 0;
    if (gy >= 0 && gy < H && gx >= 0 && gx < W) v = dgb[gy * W + gx];
    pool[RAW_OFF + i] = v;
  }
  __syncthreads();

  // ---- build im2col planes: entry (row, s) = 4 packed f16 pairs for cols s..s+7 ----
  for (int idx = tid; idx < 18 * 72; idx += 256) {
    int row = idx / 72, s = idx % 72;
    uint32_t d[8];
#pragma unroll
    for (int j = 0; j < 8; j++) d[j] = pool[RAW_OFF + row * 80 + s + j];
    u32x4 eh, el;
#pragma unroll
    for (int q = 0; q < 4; q++) {
      eh[q] = __builtin_amdgcn_perm(d[2 * q + 1], d[2 * q], 0x05040100u);
      el[q] = __builtin_amdgcn_perm(d[2 * q + 1], d[2 * q], 0x07060302u);
    }
    *(u32x4*)&pool[PH_OFF + idx * 4] = eh;
    *(u32x4*)&pool[PL_OFF + idx * 4] = el;
  }

  // ---- stage B chunk 0 ----
  {
    const uint32_t* src = Bf + (size_t)tid * 4;
    uint32_t* dst = &pool[BB_OFF + tid * 4];
    gl_lds16(src, dst);
    gl_lds16(src + 1024, dst + 1024);
    gl_lds16(src + 2048, dst + 2048);
  }
  asm volatile("s_waitcnt vmcnt(0)" ::: "memory");
  __syncthreads();

  floatx16 acc[2][3];
#pragma unroll
  for (int mt = 0; mt < 2; mt++)
#pragma unroll
    for (int t = 0; t < 3; t++)
#pragma unroll
      for (int q = 0; q < 16; q++) acc[mt][t][q] = 0.f;

  int buf = 0;
  for (int c = 0; c < 19; c++) {
    // stage next chunk into other buffer (prev-iter barrier made it free)
    if (c + 1 < 19) {
      const uint32_t* src = Bf + (size_t)(c + 1) * 3072 + (size_t)tid * 4;
      uint32_t* dst = &pool[BB_OFF + (buf ^ 1) * 3072 + tid * 4];
      gl_lds16(src, dst);
      gl_lds16(src + 1024, dst + 1024);
      gl_lds16(src + 2048, dst + 2048);
    }

    // A fragments: one b128 per half per m-tile
    FragU fah[2], fal[2];
    if (c < 17) {
#pragma unroll
      for (int mt = 0; mt < 2; mt++) {
        int e = ((r + c) * 72 + mt * 32 + nl + half * 8) * 4;
        fah[mt].u = *(const u32x4*)&pool[PH_OFF + e];
        fal[mt].u = *(const u32x4*)&pool[PL_OFF + e];
      }
    } else {
      int kyb = (c - 17) * 16 + half * 8;
#pragma unroll
      for (int mt = 0; mt < 2; mt++) {
        uint32_t d[8];
#pragma unroll
        for (int j = 0; j < 8; j++) {
          int ky = kyb + j; if (ky > 16) ky = 16;   // clamped reads killed by B=0
          d[j] = pool[RAW_OFF + (r + ky) * 80 + mt * 32 + nl + 16];
        }
#pragma unroll
        for (int q = 0; q < 4; q++) {
          fah[mt].u[q] = __builtin_amdgcn_perm(d[2 * q + 1], d[2 * q], 0x05040100u);
          fal[mt].u[q] = __builtin_amdgcn_perm(d[2 * q + 1], d[2 * q], 0x07060302u);
        }
      }
    }

    // B fragments from LDS (contiguous b128)
    FragU bh[3], bl[3];
#pragma unroll
    for (int t = 0; t < 3; t++) {
      int o = BB_OFF + buf * 3072 + g * 768 + t * 256 + lane * 4;
      bh[t].u = *(const u32x4*)&pool[o];
      bl[t].u = *(const u32x4*)&pool[o + 1536];
    }

    // MFMA, term-major: 6 independent dep-chains per term
#pragma unroll
    for (int t = 0; t < 3; t++)
#pragma unroll
      for (int mt = 0; mt < 2; mt++)
        acc[mt][t] = __builtin_amdgcn_mfma_f32_32x32x16_f16(fah[mt].h, bh[t].h, acc[mt][t], 0, 0, 0);
#pragma unroll
    for (int t = 0; t < 3; t++)
#pragma unroll
      for (int mt = 0; mt < 2; mt++)
        acc[mt][t] = __builtin_amdgcn_mfma_f32_32x32x16_f16(fal[mt].h, bh[t].h, acc[mt][t], 0, 0, 0);
#pragma unroll
    for (int t = 0; t < 3; t++)
#pragma unroll
      for (int mt = 0; mt < 2; mt++)
        acc[mt][t] = __builtin_amdgcn_mfma_f32_32x32x16_f16(fah[mt].h, bl[t].h, acc[mt][t], 0, 0, 0);

    asm volatile("s_waitcnt vmcnt(0)" ::: "memory");
    __syncthreads();
    buf ^= 1;
  }

  // ---- epilogue (aliases dead pool regions; last loop barrier protects) ----
  float* pm = (float*)&pool[0];     // [2][2][64]
  int*   pn = (int*)&pool[256];     // [2][2][64]
  float* pS = (float*)&pool[512];   // [2][2][64]
  float* pc = (float*)&pool[768];   // [2][2][64]
  int*   fn = (int*)&pool[1024];    // [2][64]
  float* fS = (float*)&pool[1152];  // [2][64]

  const float PI_F = 3.14159265358979323846f;

  // stage 1: per-wave partial argmax/sum over its 96 filters, per output pixel
#pragma unroll
  for (int mt = 0; mt < 2; mt++) {
#pragma unroll
    for (int q = 0; q < 16; q++) {
      float m = -1.f, S = 0.f;
      int bt = 0;
#pragma unroll
      for (int t = 0; t < 3; t++) {
        float v = fabsf(acc[mt][t][q]);
        S += v;
        if (v > m) { m = v; bt = t; }
      }
      int n = g * 96 + bt * 32 + nl;
#pragma unroll
      for (int msk = 1; msk < 32; msk <<= 1) {
        float vo = __shfl_xor(m, msk);
        int   no = __shfl_xor(n, msk);
        float So = __shfl_xor(S, msk);
        bool take = (vo > m) || (vo == m && no < n);
        m = take ? vo : m;
        n = take ? no : n;
        S += So;
      }
      if (nl == 0) {
        int px = mt * 32 + (q & 3) + 8 * (q >> 2) + 4 * half;
        pm[(r * 2 + g) * 64 + px] = m;
        pn[(r * 2 + g) * 64 + px] = n;
        pS[(r * 2 + g) * 64 + px] = S;
      }
    }
  }
  __syncthreads();

  // stage 2: g==0 waves combine n-groups, write orientation
  if (g == 0) {
    int p = lane;
    float m0 = pm[(r * 2 + 0) * 64 + p], m1 = pm[(r * 2 + 1) * 64 + p];
    int n = (m1 > m0) ? pn[(r * 2 + 1) * 64 + p] : pn[(r * 2 + 0) * 64 + p];
    float S = pS[(r * 2 + 0) * 64 + p] + pS[(r * 2 + 1) * 64 + p];
    fn[r * 64 + p] = n; fS[r * 64 + p] = S;
    float om = (float)n / 180.0f * 255.0f;
    out[(size_t)b * NPIX + (size_t)(y0 + r) * W + x0 + p] = om;
  }
  __syncthreads();

  // stage 3: per-wave partial confidence with the final winner
  {
    float bn[3];
#pragma unroll
    for (int t = 0; t < 3; t++) {
      int n = g * 96 + t * 32 + nl;
      bn[t] = (n < NF) ? bins[n] : 0.f;
    }
#pragma unroll
    for (int mt = 0; mt < 2; mt++) {
#pragma unroll
      for (int q = 0; q < 16; q++) {
        int px = mt * 32 + (q & 3) + 8 * (q >> 2) + 4 * half;
        int nwin = fn[r * 64 + px];
        float om = (float)nwin / 180.0f * 255.0f;
        float rad = om / 180.0f * PI_F;
        float C = 0.f;
#pragma unroll
        for (int t = 0; t < 3; t++) {
          float dd = rad - bn[t];
          float d0 = fabsf(dd);
          float d1 = fabsf(dd - PI_F);
          float d2 = fabsf(dd + PI_F);
          float d = fminf(d0, fminf(d1, d2));
          C = fmaf(d * d, fabsf(acc[mt][t][q]), C);
        }
#pragma unroll
        for (int msk = 1; msk < 32; msk <<= 1) C += __shfl_xor(C, msk);
        if (nl == 0) pc[(r * 2 + g) * 64 + px] = C;
      }
    }
  }
  __syncthreads();

  // stage 4: g==0 waves finalize confidence
  if (g == 0) {
    int p = lane;
    float C = pc[(r * 2 + 0) * 64 + p] + pc[(r * 2 + 1) * 64 + p];
    out[(size_t)NB * NPIX + (size_t)b * NPIX + (size_t)(y0 + r) * W + x0 + p] = C / fS[r * 64 + p];
  }
}

extern "C" void kernel_launch(void* const* d_in, const int* in_sizes, int n_in,
                              void* d_out, int out_size, void* d_ws, size_t ws_size,
                              hipStream_t stream) {
  const float* x = (const float*)d_in[0];      // [2,3,512,512]
  const float* wts = (const float*)d_in[1];    // [180,1,17,17]
  const float* bins = (const float*)d_in[2];   // [180]
  float* out = (float*)d_out;

  float* ws = (float*)d_ws;
  float* gray = ws;                                 // 524288 f32
  float* tmpA = ws + (size_t)NB * NPIX;             // 524288 f32
  float* tmpB = tmpA + (size_t)NB * NPIX;           // 524288 f32
  uint32_t* dogp = (uint32_t*)(tmpB + (size_t)NB * NPIX);  // 524288 u32
  float* taps = (float*)(dogp + (size_t)NB * NPIX); // 128 f32
  uint32_t* Bf = (uint32_t*)(taps + 128);           // 19*3072 u32

  k_taps<<<1, 64, 0, stream>>>(taps);
  k_repackB<<<114, 256, 0, stream>>>(wts, Bf);

  int n = NB * NPIX;
  int blk = 256, grd = (n + blk - 1) / blk;
  k_gray<<<grd, blk, 0, stream>>>(x, gray);
  k_vblur2<<<grd, blk, 0, stream>>>(gray, tmpA, tmpB, taps);
  k_hblur_dog<<<grd, blk, 0, stream>>>(tmpA, tmpB, dogp, taps);

  dim3 g(W / 64, H / 2, NB);
  k_conv<<<g, 256, 0, stream>>>(dogp, Bf, bins, out);
}